// Round 2
// baseline (584.347 us; speedup 1.0000x reference)
//
#include <hip/hip_runtime.h>

#define SDIM 196
#define BDIM 64
#define NDIM 512
#define DDIM 1024
#define HDIM 8

typedef __attribute__((ext_vector_type(8))) short short8;
typedef __attribute__((ext_vector_type(8))) unsigned short ushort8;
typedef __attribute__((ext_vector_type(4))) unsigned short ushort4v;
typedef __attribute__((ext_vector_type(4))) float f32x4;

typedef const __attribute__((address_space(1))) unsigned int* gq_ptr;
typedef __attribute__((address_space(3))) unsigned int* lds_ptr;

__device__ __forceinline__ unsigned short f2bf(float f) {
    unsigned int x = __float_as_uint(f);
    x += 0x7fffu + ((x >> 16) & 1u);   // RNE
    return (unsigned short)(x >> 16);
}

__device__ __forceinline__ float wred_sum(float v) {
#pragma unroll
    for (int off = 32; off > 0; off >>= 1) v += __shfl_down(v, off);
    return v;
}

// ---------------- input -> bf16 copy + partial sums over s (7 chunks of 28) ----------------
__global__ __launch_bounds__(256) void k_mean_cast(const float* __restrict__ in,
                                                   unsigned short* __restrict__ Abf,
                                                   float* __restrict__ gpart) {
    int idx4 = blockIdx.x * 256 + threadIdx.x;   // 0..16383 over B*D/4
    int z = blockIdx.y;                           // 0..6
    size_t base = (size_t)idx4 * 4;
    float4 acc = make_float4(0.f, 0.f, 0.f, 0.f);
    int s0 = z * 28;
    for (int s = s0; s < s0 + 28; s++) {
        float4 v = *(const float4*)(in + (size_t)s * 65536 + base);
        acc.x += v.x; acc.y += v.y; acc.z += v.z; acc.w += v.w;
        ushort4v u;
        u[0] = f2bf(v.x); u[1] = f2bf(v.y); u[2] = f2bf(v.z); u[3] = f2bf(v.w);
        *(ushort4v*)(Abf + (size_t)s * 65536 + base) = u;
    }
    *(float4*)(gpart + (size_t)z * 65536 + base) = acc;
}

// ---------------- finalize g (fp32 + bf16), write common row 0 ----------------
__global__ __launch_bounds__(256) void k_gfinal(const float* __restrict__ gpart,
                                                float* __restrict__ g,
                                                unsigned short* __restrict__ g_bf,
                                                float* __restrict__ common,
                                                unsigned short* __restrict__ common_bf) {
    int idx4 = blockIdx.x * 256 + threadIdx.x;
    size_t base = (size_t)idx4 * 4;
    float4 s = make_float4(0.f, 0.f, 0.f, 0.f);
#pragma unroll
    for (int z = 0; z < 7; z++) {
        float4 v = *(const float4*)(gpart + (size_t)z * 65536 + base);
        s.x += v.x; s.y += v.y; s.z += v.z; s.w += v.w;
    }
    const float r = 1.f / (float)SDIM;
    s.x *= r; s.y *= r; s.z *= r; s.w *= r;
    *(float4*)(g + base) = s;
    ushort4v u;
    u[0] = f2bf(s.x); u[1] = f2bf(s.y); u[2] = f2bf(s.z); u[3] = f2bf(s.w);
    *(ushort4v*)(g_bf + base) = u;
    int b = (int)(base >> 10), d = (int)(base & 1023);
    size_t o = ((size_t)b * 9) * DDIM + d;
    *(float4*)(common + o) = s;
    *(ushort4v*)(common_bf + o) = u;
}

// ---------------- all weight casts / transposes in one launch (R0 version) ----------------
// z<8: aWq[h] T ; z=8: dWq T ; z=9: dWk T ; z=10: W1 T ; z=11: W2 T ; z 12..19: aWk[h] copy-cast
__global__ __launch_bounds__(256) void k_prep_w(const float* __restrict__ aWq,
                                                const float* __restrict__ dWq,
                                                const float* __restrict__ dWk,
                                                const float* __restrict__ uW,
                                                const float* __restrict__ aWk,
                                                unsigned short* __restrict__ aWqT,
                                                unsigned short* __restrict__ dWqT,
                                                unsigned short* __restrict__ dWkT,
                                                unsigned short* __restrict__ W1t,
                                                unsigned short* __restrict__ W2T,
                                                unsigned short* __restrict__ aWkb) {
    __shared__ float tile[64][65];
    int z = blockIdx.z;
    const float* src; unsigned short* dst; bool tr = true;
    if (z < 8)       { src = aWq + (size_t)z * 1048576; dst = aWqT + (size_t)z * 1048576; }
    else if (z == 8) { src = dWq; dst = dWqT; }
    else if (z == 9) { src = dWk; dst = dWkT; }
    else if (z == 10){ src = uW;  dst = W1t; }
    else if (z == 11){ src = uW + 1048576; dst = W2T; }
    else             { src = aWk + (size_t)(z - 12) * 1048576; dst = aWkb + (size_t)(z - 12) * 1048576; tr = false; }
    int d0 = blockIdx.y * 64, e0 = blockIdx.x * 64, t = threadIdx.x;
    if (tr) {
        for (int rep = 0; rep < 16; rep++) {
            int idx = rep * 256 + t;
            int dl = idx >> 6, el = idx & 63;
            tile[dl][el] = src[(size_t)(d0 + dl) * DDIM + e0 + el];
        }
        __syncthreads();
        for (int rep = 0; rep < 16; rep++) {
            int idx = rep * 256 + t;
            int el = idx >> 6, dl = idx & 63;
            dst[(size_t)(e0 + el) * DDIM + d0 + dl] = f2bf(tile[dl][el]);
        }
    } else {
        for (int rep = 0; rep < 16; rep++) {
            int idx = rep * 256 + t;
            int dl = idx >> 6, el = idx & 63;
            size_t o = (size_t)(d0 + dl) * DDIM + e0 + el;
            dst[o] = f2bf(src[o]);
        }
    }
}

// ---------------- generic bf16 MFMA GEMM, 64x64 tile, K=1024, ld=1024 (R0 version) ----------------
__global__ __launch_bounds__(256) void k_mfma64(const unsigned short* __restrict__ A,
                                                const unsigned short* __restrict__ B0,
                                                const unsigned short* __restrict__ B1,
                                                const float* __restrict__ bias0,
                                                const float* __restrict__ bias1,
                                                float* __restrict__ C0,
                                                float* __restrict__ C1,
                                                unsigned short* __restrict__ Cbf,
                                                long sA, long sB, long sBias, long sC,
                                                int zsplit) {
    __shared__ unsigned short As[64][40];
    __shared__ unsigned short Bs[64][40];
    int z = blockIdx.z;
    const unsigned short* Bp; const float* bp; float* Cp; int zz;
    if (z < zsplit) { Bp = B0; bp = bias0; Cp = C0; zz = z; }
    else            { Bp = B1; bp = bias1; Cp = C1; zz = z - zsplit; }
    A  += (size_t)zz * sA;
    Bp += (size_t)zz * sB;
    if (bp) bp += (size_t)zz * sBias;
    Cp += (size_t)zz * sC;
    unsigned short* Cb = Cbf ? Cbf + (size_t)zz * sC : nullptr;

    int t = threadIdx.x;
    int lane = t & 63, wave = t >> 6;
    int quad = lane >> 4, l16 = lane & 15;
    int wr = wave >> 1, wc = wave & 1;
    int m0 = blockIdx.y * 64, n0 = blockIdx.x * 64;
    f32x4 acc[2][2];
#pragma unroll
    for (int i = 0; i < 2; i++)
#pragma unroll
        for (int j = 0; j < 2; j++)
#pragma unroll
            for (int rr = 0; rr < 4; rr++) acc[i][j][rr] = 0.f;
    int r = t >> 2, c = (t & 3) * 8;
    for (int k0 = 0; k0 < DDIM; k0 += 32) {
        *(ushort8*)&As[r][c] = *(const ushort8*)(A  + (size_t)(m0 + r) * DDIM + k0 + c);
        *(ushort8*)&Bs[r][c] = *(const ushort8*)(Bp + (size_t)(n0 + r) * DDIM + k0 + c);
        __syncthreads();
        short8 a0 = *(const short8*)&As[wr * 32 + l16][quad * 8];
        short8 a1 = *(const short8*)&As[wr * 32 + 16 + l16][quad * 8];
        short8 b0 = *(const short8*)&Bs[wc * 32 + l16][quad * 8];
        short8 b1 = *(const short8*)&Bs[wc * 32 + 16 + l16][quad * 8];
        acc[0][0] = __builtin_amdgcn_mfma_f32_16x16x32_bf16(a0, b0, acc[0][0], 0, 0, 0);
        acc[0][1] = __builtin_amdgcn_mfma_f32_16x16x32_bf16(a0, b1, acc[0][1], 0, 0, 0);
        acc[1][0] = __builtin_amdgcn_mfma_f32_16x16x32_bf16(a1, b0, acc[1][0], 0, 0, 0);
        acc[1][1] = __builtin_amdgcn_mfma_f32_16x16x32_bf16(a1, b1, acc[1][1], 0, 0, 0);
        __syncthreads();
    }
#pragma unroll
    for (int tm = 0; tm < 2; tm++)
#pragma unroll
        for (int tn = 0; tn < 2; tn++) {
            int col = n0 + wc * 32 + tn * 16 + l16;
            float bb = bp ? bp[col] : 0.f;
#pragma unroll
            for (int rr = 0; rr < 4; rr++) {
                int m = m0 + wr * 32 + tm * 16 + quad * 4 + rr;
                float v = acc[tm][tn][rr] + bb;
                Cp[(size_t)m * DDIM + col] = v;
                if (Cb) Cb[(size_t)m * DDIM + col] = f2bf(v);
            }
        }
}

// ---------------- qkb[b*8+h] = Q[h,b,:]·abk[h,:] (one shot, grid 64) ----------------
__global__ __launch_bounds__(256) void k_qkb(const float* __restrict__ Q,
                                             const float* __restrict__ abk,
                                             float* __restrict__ qkb) {
    int b = blockIdx.x;
    int wave = threadIdx.x >> 6, lane = threadIdx.x & 63;
    for (int h = wave; h < 8; h += 4) {
        const float* q = Q + ((size_t)(h * 64 + b) << 10);
        const float* bk = abk + ((size_t)h << 10);
        float a = 0.f;
        for (int e = lane; e < 1024; e += 64) a += q[e] * bk[e];
        a = wred_sum(a);
        if (lane == 0) qkb[b * 8 + h] = a;
    }
}

// ---------------- fused aggregated attention, head-split waves ----------------
// grid (16, B): 16 chunks of 32 n-rows. Each wave owns 2 heads (private m,l,O,Q-regs).
// LDS = srow only (32KB) -> 4 blocks/CU. 2 barriers per 8-row tile.
__global__ __launch_bounds__(256) void k_agg(const float* __restrict__ gn,
                                             const float* __restrict__ Qt,
                                             const float* __restrict__ qkb,
                                             float* __restrict__ Opart,
                                             float* __restrict__ ml) {
    int b = blockIdx.y, chunk = blockIdx.x, t = threadIdx.x;
    int wave = t >> 6, lane = t & 63;
    __shared__ float srow[8][1024];   // 32KB
    int h0 = wave * 2;
    // Q fragments in registers: q[hh][j] covers d = j*256 + lane*4 .. +3
    float4 q[2][4];
#pragma unroll
    for (int hh = 0; hh < 2; hh++)
#pragma unroll
        for (int j = 0; j < 4; j++)
            q[hh][j] = *(const float4*)(Qt + ((size_t)((h0 + hh) * 64 + b) << 10) + j * 256 + lane * 4);
    float qb0 = qkb[b * 8 + h0], qb1 = qkb[b * 8 + h0 + 1];
    float4 O[2][4];
    float m0h = -1e30f, m1h = -1e30f, l0 = 0.f, l1 = 0.f;
#pragma unroll
    for (int hh = 0; hh < 2; hh++)
#pragma unroll
        for (int j = 0; j < 4; j++) O[hh][j] = make_float4(0.f, 0.f, 0.f, 0.f);
    const float* gnb = gn + (((size_t)b * NDIM + chunk * 32) << 10);

    for (int tile = 0; tile < 4; tile++) {
        if (tile) __syncthreads();   // previous tile's consumers done
        // cooperative stage: wave stages rows 2*wave, 2*wave+1 of this 8-row tile
#pragma unroll
        for (int rr = 0; rr < 2; rr++) {
            const float* src = gnb + ((size_t)(tile * 8 + wave * 2 + rr) << 10);
#pragma unroll
            for (int j = 0; j < 4; j++)
                *(float4*)&srow[wave * 2 + rr][j * 256 + lane * 4] = *(const float4*)(src + j * 256 + lane * 4);
        }
        __syncthreads();
        // scores for this wave's 2 heads x 8 rows (fp32 exact, butterfly reduce)
        float e0[8], e1[8];
        {
            float s0[8], s1[8];
#pragma unroll
            for (int r = 0; r < 8; r++) {
                float a0 = 0.f, a1 = 0.f;
#pragma unroll
                for (int j = 0; j < 4; j++) {
                    float4 v = *(const float4*)&srow[r][j * 256 + lane * 4];
                    a0 += q[0][j].x * v.x + q[0][j].y * v.y + q[0][j].z * v.z + q[0][j].w * v.w;
                    a1 += q[1][j].x * v.x + q[1][j].y * v.y + q[1][j].z * v.z + q[1][j].w * v.w;
                }
#pragma unroll
                for (int off = 32; off > 0; off >>= 1) {
                    a0 += __shfl_xor(a0, off);
                    a1 += __shfl_xor(a1, off);
                }
                s0[r] = (a0 + qb0) * 0.03125f;
                s1[r] = (a1 + qb1) * 0.03125f;
            }
            float tm0 = s0[0], tm1 = s1[0];
#pragma unroll
            for (int r = 1; r < 8; r++) { tm0 = fmaxf(tm0, s0[r]); tm1 = fmaxf(tm1, s1[r]); }
            float mn0 = fmaxf(m0h, tm0), mn1 = fmaxf(m1h, tm1);
            float al0 = __expf(m0h - mn0), al1 = __expf(m1h - mn1);
            m0h = mn0; m1h = mn1;
            l0 *= al0; l1 *= al1;
#pragma unroll
            for (int j = 0; j < 4; j++) {
                O[0][j].x *= al0; O[0][j].y *= al0; O[0][j].z *= al0; O[0][j].w *= al0;
                O[1][j].x *= al1; O[1][j].y *= al1; O[1][j].z *= al1; O[1][j].w *= al1;
            }
#pragma unroll
            for (int r = 0; r < 8; r++) {
                e0[r] = __expf(s0[r] - mn0);
                e1[r] = __expf(s1[r] - mn1);
                l0 += e0[r]; l1 += e1[r];
            }
        }
        // O update: re-read srow at own d-slice
#pragma unroll
        for (int r = 0; r < 8; r++) {
#pragma unroll
            for (int j = 0; j < 4; j++) {
                float4 v = *(const float4*)&srow[r][j * 256 + lane * 4];
                O[0][j].x += e0[r] * v.x; O[0][j].y += e0[r] * v.y;
                O[0][j].z += e0[r] * v.z; O[0][j].w += e0[r] * v.w;
                O[1][j].x += e1[r] * v.x; O[1][j].y += e1[r] * v.y;
                O[1][j].z += e1[r] * v.z; O[1][j].w += e1[r] * v.w;
            }
        }
    }
    // write partials
    size_t pb = ((size_t)chunk * 64 + b) * 8;
#pragma unroll
    for (int hh = 0; hh < 2; hh++)
#pragma unroll
        for (int j = 0; j < 4; j++)
            *(float4*)(Opart + (pb + h0 + hh) * 1024 + j * 256 + lane * 4) = O[hh][j];
    if (lane == 0) {
        ml[(pb + h0) * 2 + 0] = m0h;
        ml[(pb + h0) * 2 + 1] = l0;
        ml[(pb + h0 + 1) * 2 + 0] = m1h;
        ml[(pb + h0 + 1) * 2 + 1] = l1;
    }
}

// ---------------- combine 16 chunk-partials -> common rows 1..8 (+bf16) ----------------
__global__ __launch_bounds__(256) void k_agg_reduce(const float* __restrict__ Opart,
                                                    const float* __restrict__ ml,
                                                    float* __restrict__ common,
                                                    unsigned short* __restrict__ common_bf) {
    int b = blockIdx.y, t = threadIdx.x;
    int d = blockIdx.x * 256 + t;
#pragma unroll
    for (int h = 0; h < 8; h++) {
        float mc[16], lc[16];
        float M = -1e30f;
#pragma unroll
        for (int c = 0; c < 16; c++) {
            size_t p = (((size_t)c * 64 + b) * 8 + h) * 2;
            mc[c] = ml[p]; lc[c] = ml[p + 1];
            M = fmaxf(M, mc[c]);
        }
        float den = 0.f, num = 0.f;
#pragma unroll
        for (int c = 0; c < 16; c++) {
            float sc = __expf(mc[c] - M);
            den += sc * lc[c];
            num += sc * Opart[(((size_t)c * 64 + b) * 8 + h) * 1024 + d];
        }
        float o = num / den;
        size_t off = ((size_t)(b * 9 + 1 + h) << 10) + d;
        common[off] = o;
        common_bf[off] = f2bf(o);
    }
}

// ---------------- 9x9 attention + diff -> bf16, grid (B) ----------------
__global__ __launch_bounds__(256) void k_diff(const float* __restrict__ Qd,
                                              const float* __restrict__ Kd,
                                              const float* __restrict__ common,
                                              const float* __restrict__ g,
                                              unsigned short* __restrict__ diffb_bf) {
    int b = blockIdx.x, t = threadIdx.x;
    int wave = t >> 6, lane = t & 63;
    __shared__ float sQ[9 * 1024];
    __shared__ float sK[9 * 1024];
    __shared__ float smd[81];
    __shared__ float sw[9];
    const float* Qb = Qd + (size_t)b * 9216;
    const float* Kb = Kd + (size_t)b * 9216;
    for (int i = t; i < 2304; i += 256) {
        *(float4*)&sQ[i * 4] = *(const float4*)(Qb + (size_t)i * 4);
        *(float4*)&sK[i * 4] = *(const float4*)(Kb + (size_t)i * 4);
    }
    __syncthreads();
    for (int p = wave; p < 81; p += 4) {
        int i = p / 9, j = p % 9;
        const float* qi = sQ + i * 1024;
        const float* kj = sK + j * 1024;
        float a = 0.f;
#pragma unroll
        for (int jj = 0; jj < 4; jj++) {
            float4 q = *(const float4*)(qi + jj * 256 + lane * 4);
            float4 k = *(const float4*)(kj + jj * 256 + lane * 4);
            a += q.x * k.x + q.y * k.y + q.z * k.z + q.w * k.w;
        }
        a = wred_sum(a);
        if (lane == 0) smd[p] = a * 0.03125f;
    }
    __syncthreads();
    if (t < 9) {
        float mx = -1e30f;
        for (int j = 0; j < 9; j++) mx = fmaxf(mx, smd[t * 9 + j]);
        float e[9], s = 0.f;
        for (int j = 0; j < 9; j++) { e[j] = __expf(smd[t * 9 + j] - mx); s += e[j]; }
        float inv = 1.f / s;
        for (int j = 0; j < 9; j++) smd[t * 9 + j] = e[j] * inv;
    }
    __syncthreads();
    if (t < 9) {
        float a = 0.f;
        for (int i = 0; i < 9; i++) a += smd[i * 9 + t];
        sw[t] = a * (1.f / 9.f);
    }
    __syncthreads();
    int d = t * 4;
    float4 ci = make_float4(0.f, 0.f, 0.f, 0.f);
#pragma unroll
    for (int j = 0; j < 9; j++) {
        float w = sw[j];
        float4 cv = *(const float4*)(common + ((size_t)(b * 9 + j) << 10) + d);
        ci.x += w * cv.x; ci.y += w * cv.y; ci.z += w * cv.z; ci.w += w * cv.w;
    }
    float4 gv = *(const float4*)(g + ((size_t)b << 10) + d);
    ushort4v u;
    u[0] = f2bf(gv.x - ci.x); u[1] = f2bf(gv.y - ci.y);
    u[2] = f2bf(gv.z - ci.z); u[3] = f2bf(gv.w - ci.w);
    *(ushort4v*)(diffb_bf + ((size_t)b << 10) + d) = u;
}

// ---------------- main GEMM: relu(Abf@W1t^T + dt2[b]) -> out. 128x128, BK=64, lds-dma ----------------
__global__ __launch_bounds__(256) void k_gemm_main(const unsigned short* __restrict__ A,
                                                   const unsigned short* __restrict__ Bw,
                                                   const float* __restrict__ dt2,
                                                   float* __restrict__ out) {
    __shared__ unsigned short As[128 * 64];
    __shared__ unsigned short Bs[128 * 64];
    int t = threadIdx.x;
    int lane = t & 63, wave = t >> 6;
    int quad = lane >> 4, l16 = lane & 15;
    int wr = wave >> 1, wc = wave & 1;
    int m0 = blockIdx.y * 128, n0 = blockIdx.x * 128;
    f32x4 acc[4][4];
#pragma unroll
    for (int i = 0; i < 4; i++)
#pragma unroll
        for (int j = 0; j < 4; j++)
#pragma unroll
            for (int rr = 0; rr < 4; rr++) acc[i][j][rr] = 0.f;

    for (int k0 = 0; k0 < DDIM; k0 += 64) {
#pragma unroll
        for (int cc = 0; cc < 4; cc++) {
            int o = cc * 4096 + t * 16;
            int r = o >> 7;
            int ke = (o & 127) >> 1;
            __builtin_amdgcn_global_load_lds(
                (gq_ptr)(const void*)(A + (size_t)(m0 + r) * DDIM + k0 + ke),
                (lds_ptr)(void*)((char*)As + o), 16, 0, 0);
            __builtin_amdgcn_global_load_lds(
                (gq_ptr)(const void*)(Bw + (size_t)(n0 + r) * DDIM + k0 + ke),
                (lds_ptr)(void*)((char*)Bs + o), 16, 0, 0);
        }
        __syncthreads();
#pragma unroll
        for (int ks = 0; ks < 2; ks++) {
            short8 af[4], bf[4];
#pragma unroll
            for (int tm = 0; tm < 4; tm++)
                af[tm] = *(const short8*)(As + (wr * 64 + tm * 16 + l16) * 64 + ks * 32 + quad * 8);
#pragma unroll
            for (int tn = 0; tn < 4; tn++)
                bf[tn] = *(const short8*)(Bs + (wc * 64 + tn * 16 + l16) * 64 + ks * 32 + quad * 8);
#pragma unroll
            for (int tm = 0; tm < 4; tm++)
#pragma unroll
                for (int tn = 0; tn < 4; tn++)
                    acc[tm][tn] = __builtin_amdgcn_mfma_f32_16x16x32_bf16(af[tm], bf[tn], acc[tm][tn], 0, 0, 0);
        }
        __syncthreads();
    }
#pragma unroll
    for (int tm = 0; tm < 4; tm++)
#pragma unroll
        for (int tn = 0; tn < 4; tn++) {
            int col = n0 + wc * 64 + tn * 16 + l16;
#pragma unroll
            for (int rr = 0; rr < 4; rr++) {
                int m = m0 + wr * 64 + tm * 16 + quad * 4 + rr;
                float v = acc[tm][tn][rr] + dt2[((size_t)(m & 63) << 10) + col];
                out[((size_t)m << 10) + col] = fmaxf(v, 0.f);
            }
        }
}

// ---------------- in-place LayerNorm over D ----------------
__global__ __launch_bounds__(256) void k_ln(float* __restrict__ io,
                                            const float* __restrict__ gamma,
                                            const float* __restrict__ beta) {
    size_t row = blockIdx.x;
    float* p = io + row * DDIM;
    int t = threadIdx.x;
    float4 v = *(const float4*)(p + t * 4);
    float s = v.x + v.y + v.z + v.w;
    float s2 = v.x * v.x + v.y * v.y + v.z * v.z + v.w * v.w;
    s = wred_sum(s);
    s2 = wred_sum(s2);
    __shared__ float r1[4], r2[4], mv[2];
    int wave = t >> 6, lane = t & 63;
    if (lane == 0) { r1[wave] = s; r2[wave] = s2; }
    __syncthreads();
    if (t == 0) {
        float S = r1[0] + r1[1] + r1[2] + r1[3];
        float S2 = r2[0] + r2[1] + r2[2] + r2[3];
        float mean = S * (1.f / DDIM);
        float var = S2 * (1.f / DDIM) - mean * mean;
        mv[0] = mean;
        mv[1] = rsqrtf(var + 1e-5f);
    }
    __syncthreads();
    float mean = mv[0], rstd = mv[1];
    float4 gg = *(const float4*)(gamma + t * 4);
    float4 bb = *(const float4*)(beta + t * 4);
    float4 o;
    o.x = (v.x - mean) * rstd * gg.x + bb.x;
    o.y = (v.y - mean) * rstd * gg.y + bb.y;
    o.z = (v.z - mean) * rstd * gg.z + bb.z;
    o.w = (v.w - mean) * rstd * gg.w + bb.w;
    *(float4*)(p + t * 4) = o;
}

extern "C" void kernel_launch(void* const* d_in, const int* in_sizes, int n_in,
                              void* d_out, int out_size, void* d_ws, size_t ws_size,
                              hipStream_t stream) {
    (void)in_sizes; (void)n_in; (void)out_size; (void)ws_size;
    const float* input = (const float*)d_in[0];
    const float* gn    = (const float*)d_in[1];
    const float* aWq   = (const float*)d_in[2];
    const float* abq   = (const float*)d_in[3];
    const float* aWk   = (const float*)d_in[4];
    const float* abk   = (const float*)d_in[5];
    const float* dWq   = (const float*)d_in[6];
    const float* dbq   = (const float*)d_in[7];
    const float* dWk   = (const float*)d_in[8];
    const float* dbk   = (const float*)d_in[9];
    const float* uW    = (const float*)d_in[10];
    const float* ub    = (const float*)d_in[11];
    const float* lng   = (const float*)d_in[12];
    const float* lnb   = (const float*)d_in[13];
    float* out = (float*)d_out;

    float* ws = (float*)d_ws;
    float* g      = ws;                       // 65536
    float* gpart  = g + 65536;                // 458752
    float* Q      = gpart + 458752;           // 524288  [h][b][d]
    float* Qt     = Q + 524288;               // 524288  [h][b][d]
    float* common = Qt + 524288;              // 589824  [b][9][d]
    float* dt2    = common + 589824;          // 65536
    float* Opart  = dt2 + 65536;              // 8388608 [c][b][h][d], 16 chunks
    float* ml     = Opart + 8388608;          // 16384
    float* qkb    = ml + 16384;               // 512
    float* Qd     = Opart;                    // alias: Opart dead after k_agg_reduce
    float* Kd     = Opart + 589824;
    unsigned short* Abf  = (unsigned short*)(qkb + 512);   // 12845056
    unsigned short* W1t  = Abf + 12845056;    // 1048576
    unsigned short* W2T  = W1t + 1048576;     // 1048576
    unsigned short* aWqT = W2T + 1048576;     // 8388608
    unsigned short* aWkb = aWqT + 8388608;    // 8388608
    unsigned short* dWqT = aWkb + 8388608;    // 1048576
    unsigned short* dWkT = dWqT + 1048576;    // 1048576
    unsigned short* g_bf = dWkT + 1048576;    // 65536
    unsigned short* Qbf  = g_bf + 65536;      // 524288
    unsigned short* cmbf = Qbf + 524288;      // 589824
    unsigned short* dfbf = cmbf + 589824;     // 65536

    k_prep_w<<<dim3(16, 16, 20), 256, 0, stream>>>(aWq, dWq, dWk, uW, aWk,
                                                   aWqT, dWqT, dWkT, W1t, W2T, aWkb);
    k_mean_cast<<<dim3(64, 7), 256, 0, stream>>>(input, Abf, gpart);
    k_gfinal<<<64, 256, 0, stream>>>(gpart, g, g_bf, common, cmbf);
    // Q[h,b,:] = g@aWqT[h] + abq[h]  (fp32 + bf16)
    k_mfma64<<<dim3(16, 1, 8), 256, 0, stream>>>(g_bf, aWqT, nullptr, abq, nullptr,
        Q, nullptr, Qbf, 0L, 1048576L, 1024L, 65536L, 8);
    // Qt[h,b,:] = Qbf[h]@aWkb[h]
    k_mfma64<<<dim3(16, 1, 8), 256, 0, stream>>>(Qbf, aWkb, nullptr, nullptr, nullptr,
        Qt, nullptr, nullptr, 65536L, 1048576L, 0L, 65536L, 8);
    k_qkb<<<64, 256, 0, stream>>>(Q, abk, qkb);
    k_agg<<<dim3(16, BDIM), 256, 0, stream>>>(gn, Qt, qkb, Opart, ml);
    k_agg_reduce<<<dim3(4, BDIM), 256, 0, stream>>>(Opart, ml, common, cmbf);
    // Qd = common@dWqT + dbq ; Kd = common@dWkT + dbk
    k_mfma64<<<dim3(16, 9, 2), 256, 0, stream>>>(cmbf, dWqT, dWkT, dbq, dbk,
        Qd, Kd, nullptr, 0L, 0L, 0L, 0L, 1);
    k_diff<<<BDIM, 256, 0, stream>>>(Qd, Kd, common, g, dfbf);
    // dt2 = diffb@W2 + ub
    k_mfma64<<<dim3(16, 1, 1), 256, 0, stream>>>(dfbf, W2T, nullptr, ub, nullptr,
        dt2, nullptr, nullptr, 0L, 0L, 0L, 0L, 1);
    k_gemm_main<<<dim3(8, 98), 256, 0, stream>>>(Abf, W1t, dt2, out);
    k_ln<<<SDIM * BDIM, 256, 0, stream>>>(out, lng, lnb);
}

// Round 3
// 563.288 us; speedup vs baseline: 1.0374x; 1.0374x over previous
//
#include <hip/hip_runtime.h>

#define SDIM 196
#define BDIM 64
#define NDIM 512
#define DDIM 1024
#define HDIM 8

typedef __attribute__((ext_vector_type(8))) short short8;
typedef __attribute__((ext_vector_type(8))) unsigned short ushort8;
typedef __attribute__((ext_vector_type(4))) unsigned short ushort4v;
typedef __attribute__((ext_vector_type(4))) float f32x4;

typedef const __attribute__((address_space(1))) unsigned int* gq_ptr;
typedef __attribute__((address_space(3))) unsigned int* lds_ptr;

__device__ __forceinline__ unsigned short f2bf(float f) {
    unsigned int x = __float_as_uint(f);
    x += 0x7fffu + ((x >> 16) & 1u);   // RNE
    return (unsigned short)(x >> 16);
}

__device__ __forceinline__ float wred_sum(float v) {
#pragma unroll
    for (int off = 32; off > 0; off >>= 1) v += __shfl_down(v, off);
    return v;
}

// ---------------- input -> bf16 copy + partial sums over s (7 chunks of 28) ----------------
__global__ __launch_bounds__(256) void k_mean_cast(const float* __restrict__ in,
                                                   unsigned short* __restrict__ Abf,
                                                   float* __restrict__ gpart) {
    int idx4 = blockIdx.x * 256 + threadIdx.x;   // 0..16383 over B*D/4
    int z = blockIdx.y;                           // 0..6
    size_t base = (size_t)idx4 * 4;
    float4 acc = make_float4(0.f, 0.f, 0.f, 0.f);
    int s0 = z * 28;
    for (int s = s0; s < s0 + 28; s++) {
        float4 v = *(const float4*)(in + (size_t)s * 65536 + base);
        acc.x += v.x; acc.y += v.y; acc.z += v.z; acc.w += v.w;
        ushort4v u;
        u[0] = f2bf(v.x); u[1] = f2bf(v.y); u[2] = f2bf(v.z); u[3] = f2bf(v.w);
        *(ushort4v*)(Abf + (size_t)s * 65536 + base) = u;
    }
    *(float4*)(gpart + (size_t)z * 65536 + base) = acc;
}

// ---------------- finalize g (fp32 + bf16), write common row 0 ----------------
__global__ __launch_bounds__(256) void k_gfinal(const float* __restrict__ gpart,
                                                float* __restrict__ g,
                                                unsigned short* __restrict__ g_bf,
                                                float* __restrict__ common,
                                                unsigned short* __restrict__ common_bf) {
    int idx4 = blockIdx.x * 256 + threadIdx.x;
    size_t base = (size_t)idx4 * 4;
    float4 s = make_float4(0.f, 0.f, 0.f, 0.f);
#pragma unroll
    for (int z = 0; z < 7; z++) {
        float4 v = *(const float4*)(gpart + (size_t)z * 65536 + base);
        s.x += v.x; s.y += v.y; s.z += v.z; s.w += v.w;
    }
    const float r = 1.f / (float)SDIM;
    s.x *= r; s.y *= r; s.z *= r; s.w *= r;
    *(float4*)(g + base) = s;
    ushort4v u;
    u[0] = f2bf(s.x); u[1] = f2bf(s.y); u[2] = f2bf(s.z); u[3] = f2bf(s.w);
    *(ushort4v*)(g_bf + base) = u;
    int b = (int)(base >> 10), d = (int)(base & 1023);
    size_t o = ((size_t)b * 9) * DDIM + d;
    *(float4*)(common + o) = s;
    *(ushort4v*)(common_bf + o) = u;
}

// ---------------- all weight casts / transposes in one launch ----------------
// z<8: aWq[h] T ; z=8: dWq T ; z=9: dWk T ; z=10: W1 T ; z=11: W2 T ; z 12..19: aWk[h] copy-cast
__global__ __launch_bounds__(256) void k_prep_w(const float* __restrict__ aWq,
                                                const float* __restrict__ dWq,
                                                const float* __restrict__ dWk,
                                                const float* __restrict__ uW,
                                                const float* __restrict__ aWk,
                                                unsigned short* __restrict__ aWqT,
                                                unsigned short* __restrict__ dWqT,
                                                unsigned short* __restrict__ dWkT,
                                                unsigned short* __restrict__ W1t,
                                                unsigned short* __restrict__ W2T,
                                                unsigned short* __restrict__ aWkb) {
    __shared__ float tile[64][65];
    int z = blockIdx.z;
    const float* src; unsigned short* dst; bool tr = true;
    if (z < 8)       { src = aWq + (size_t)z * 1048576; dst = aWqT + (size_t)z * 1048576; }
    else if (z == 8) { src = dWq; dst = dWqT; }
    else if (z == 9) { src = dWk; dst = dWkT; }
    else if (z == 10){ src = uW;  dst = W1t; }
    else if (z == 11){ src = uW + 1048576; dst = W2T; }
    else             { src = aWk + (size_t)(z - 12) * 1048576; dst = aWkb + (size_t)(z - 12) * 1048576; tr = false; }
    int d0 = blockIdx.y * 64, e0 = blockIdx.x * 64, t = threadIdx.x;
    if (tr) {
        for (int rep = 0; rep < 16; rep++) {
            int idx = rep * 256 + t;
            int dl = idx >> 6, el = idx & 63;
            tile[dl][el] = src[(size_t)(d0 + dl) * DDIM + e0 + el];
        }
        __syncthreads();
        for (int rep = 0; rep < 16; rep++) {
            int idx = rep * 256 + t;
            int el = idx >> 6, dl = idx & 63;
            dst[(size_t)(e0 + el) * DDIM + d0 + dl] = f2bf(tile[dl][el]);
        }
    } else {
        for (int rep = 0; rep < 16; rep++) {
            int idx = rep * 256 + t;
            int dl = idx >> 6, el = idx & 63;
            size_t o = (size_t)(d0 + dl) * DDIM + e0 + el;
            dst[o] = f2bf(src[o]);
        }
    }
}

// ---------------- generic bf16 MFMA GEMM, 64x64 tile, K=1024, ld=1024 ----------------
__global__ __launch_bounds__(256) void k_mfma64(const unsigned short* __restrict__ A,
                                                const unsigned short* __restrict__ B0,
                                                const unsigned short* __restrict__ B1,
                                                const float* __restrict__ bias0,
                                                const float* __restrict__ bias1,
                                                float* __restrict__ C0,
                                                float* __restrict__ C1,
                                                unsigned short* __restrict__ Cbf,
                                                long sA, long sB, long sBias, long sC,
                                                int zsplit) {
    __shared__ unsigned short As[64][40];
    __shared__ unsigned short Bs[64][40];
    int z = blockIdx.z;
    const unsigned short* Bp; const float* bp; float* Cp; int zz;
    if (z < zsplit) { Bp = B0; bp = bias0; Cp = C0; zz = z; }
    else            { Bp = B1; bp = bias1; Cp = C1; zz = z - zsplit; }
    A  += (size_t)zz * sA;
    Bp += (size_t)zz * sB;
    if (bp) bp += (size_t)zz * sBias;
    Cp += (size_t)zz * sC;
    unsigned short* Cb = Cbf ? Cbf + (size_t)zz * sC : nullptr;

    int t = threadIdx.x;
    int lane = t & 63, wave = t >> 6;
    int quad = lane >> 4, l16 = lane & 15;
    int wr = wave >> 1, wc = wave & 1;
    int m0 = blockIdx.y * 64, n0 = blockIdx.x * 64;
    f32x4 acc[2][2];
#pragma unroll
    for (int i = 0; i < 2; i++)
#pragma unroll
        for (int j = 0; j < 2; j++)
#pragma unroll
            for (int rr = 0; rr < 4; rr++) acc[i][j][rr] = 0.f;
    int r = t >> 2, c = (t & 3) * 8;
    for (int k0 = 0; k0 < DDIM; k0 += 32) {
        *(ushort8*)&As[r][c] = *(const ushort8*)(A  + (size_t)(m0 + r) * DDIM + k0 + c);
        *(ushort8*)&Bs[r][c] = *(const ushort8*)(Bp + (size_t)(n0 + r) * DDIM + k0 + c);
        __syncthreads();
        short8 a0 = *(const short8*)&As[wr * 32 + l16][quad * 8];
        short8 a1 = *(const short8*)&As[wr * 32 + 16 + l16][quad * 8];
        short8 b0 = *(const short8*)&Bs[wc * 32 + l16][quad * 8];
        short8 b1 = *(const short8*)&Bs[wc * 32 + 16 + l16][quad * 8];
        acc[0][0] = __builtin_amdgcn_mfma_f32_16x16x32_bf16(a0, b0, acc[0][0], 0, 0, 0);
        acc[0][1] = __builtin_amdgcn_mfma_f32_16x16x32_bf16(a0, b1, acc[0][1], 0, 0, 0);
        acc[1][0] = __builtin_amdgcn_mfma_f32_16x16x32_bf16(a1, b0, acc[1][0], 0, 0, 0);
        acc[1][1] = __builtin_amdgcn_mfma_f32_16x16x32_bf16(a1, b1, acc[1][1], 0, 0, 0);
        __syncthreads();
    }
#pragma unroll
    for (int tm = 0; tm < 2; tm++)
#pragma unroll
        for (int tn = 0; tn < 2; tn++) {
            int col = n0 + wc * 32 + tn * 16 + l16;
            float bb = bp ? bp[col] : 0.f;
#pragma unroll
            for (int rr = 0; rr < 4; rr++) {
                int m = m0 + wr * 32 + tm * 16 + quad * 4 + rr;
                float v = acc[tm][tn][rr] + bb;
                Cp[(size_t)m * DDIM + col] = v;
                if (Cb) Cb[(size_t)m * DDIM + col] = f2bf(v);
            }
        }
}

// ---------------- qkb[b*8+h] = Q[h,b,:]·abk[h,:] (one shot, grid 64) ----------------
__global__ __launch_bounds__(256) void k_qkb(const float* __restrict__ Q,
                                             const float* __restrict__ abk,
                                             float* __restrict__ qkb) {
    int b = blockIdx.x;
    int wave = threadIdx.x >> 6, lane = threadIdx.x & 63;
    for (int h = wave; h < 8; h += 4) {
        const float* q = Q + ((size_t)(h * 64 + b) << 10);
        const float* bk = abk + ((size_t)h << 10);
        float a = 0.f;
        for (int e = lane; e < 1024; e += 64) a += q[e] * bk[e];
        a = wred_sum(a);
        if (lane == 0) qkb[b * 8 + h] = a;
    }
}

// ---------------- fused aggregated attention v3 ----------------
// grid (16, B): 16 chunks of 32 n-rows, 8 tiles of 4 rows, double-buffered
// global_load_lds staging. Wave owns 2 heads (Q in regs); O per-thread d-slice.
// LDS 33KB -> 4 blocks/CU; shfl_down reductions only.
__global__ __launch_bounds__(256, 4) void k_agg(const float* __restrict__ gn,
                                                const float* __restrict__ Qt,
                                                const float* __restrict__ qkb,
                                                float* __restrict__ Opart,
                                                float* __restrict__ ml) {
    int b = blockIdx.y, chunk = blockIdx.x, t = threadIdx.x;
    int wave = t >> 6, lane = t & 63;
    __shared__ float srow[2][4][1024];   // 32KB, double-buffered 4-row tiles
    __shared__ float sEt[4][8];          // e[row][head]
    __shared__ float sAl[8];             // alpha[head]
    int h0 = wave * 2;
    const float* gnb = gn + (((size_t)b * NDIM + chunk * 32) << 10);

    // Q fragments in registers: q[hh][j] covers d = j*256 + lane*4 .. +3
    float4 q[2][4];
#pragma unroll
    for (int hh = 0; hh < 2; hh++)
#pragma unroll
        for (int j = 0; j < 4; j++)
            q[hh][j] = *(const float4*)(Qt + ((size_t)((h0 + hh) * 64 + b) << 10) + j * 256 + lane * 4);
    float qb0 = qkb[b * 8 + h0], qb1 = qkb[b * 8 + h0 + 1];

    float O[8][4];
    float m0h = -1e30f, m1h = -1e30f, l0 = 0.f, l1 = 0.f;
#pragma unroll
    for (int h = 0; h < 8; h++)
#pragma unroll
        for (int j = 0; j < 4; j++) O[h][j] = 0.f;

    // stage(tile, buf): 4 rows x 4KB via global_load_lds (dest = uniform base + lane*16)
    // lds byte off = buf*16384 + c*4096 + wave*1024 + lane*16
    // global       = gnb + (tile*4+c)*1024 + wave*256 + lane*4   (floats)
#define STAGE(TILE, BUF)                                                             \
    {                                                                                \
        _Pragma("unroll")                                                            \
        for (int c = 0; c < 4; c++) {                                                \
            __builtin_amdgcn_global_load_lds(                                        \
                (gq_ptr)(const void*)(gnb + (((size_t)(TILE) * 4 + c) << 10) +       \
                                      wave * 256 + lane * 4),                        \
                (lds_ptr)(void*)((char*)srow + (BUF) * 16384 + c * 4096 +            \
                                 wave * 1024 + lane * 16),                           \
                16, 0, 0);                                                           \
        }                                                                            \
    }

    STAGE(0, 0);
    int cur = 0;
    for (int tile = 0; tile < 8; tile++) {
        __syncthreads();   // buf[cur] loads drained; prev O-update (reading buf[cur^1]) done
        if (tile < 7) STAGE(tile + 1, cur ^ 1);   // async prefetch under score phase
        const float (*rows)[1024] = srow[cur];
        // scores: this wave's 2 heads x 4 rows (fp32 exact)
        float s0[4], s1[4];
#pragma unroll
        for (int r = 0; r < 4; r++) {
            float a0 = 0.f, a1 = 0.f;
#pragma unroll
            for (int j = 0; j < 4; j++) {
                float4 v = *(const float4*)&rows[r][j * 256 + lane * 4];
                a0 += q[0][j].x * v.x + q[0][j].y * v.y + q[0][j].z * v.z + q[0][j].w * v.w;
                a1 += q[1][j].x * v.x + q[1][j].y * v.y + q[1][j].z * v.z + q[1][j].w * v.w;
            }
            s0[r] = wred_sum(a0);
            s1[r] = wred_sum(a1);
        }
        // lane 0: softmax bookkeeping for this wave's 2 heads (wave-uniform outputs via LDS)
        if (lane == 0) {
#pragma unroll
            for (int r = 0; r < 4; r++) {
                s0[r] = (s0[r] + qb0) * 0.03125f;
                s1[r] = (s1[r] + qb1) * 0.03125f;
            }
            float tm0 = fmaxf(fmaxf(s0[0], s0[1]), fmaxf(s0[2], s0[3]));
            float tm1 = fmaxf(fmaxf(s1[0], s1[1]), fmaxf(s1[2], s1[3]));
            float mn0 = fmaxf(m0h, tm0), mn1 = fmaxf(m1h, tm1);
            float al0 = __expf(m0h - mn0), al1 = __expf(m1h - mn1);
            m0h = mn0; m1h = mn1;
            l0 *= al0; l1 *= al1;
            sAl[h0] = al0; sAl[h0 + 1] = al1;
#pragma unroll
            for (int r = 0; r < 4; r++) {
                float e0 = __expf(s0[r] - mn0);
                float e1 = __expf(s1[r] - mn1);
                l0 += e0; l1 += e1;
                sEt[r][h0] = e0; sEt[r][h0 + 1] = e1;
            }
        }
        __syncthreads();   // sEt/sAl ready (also drains prefetch; score phase covered latency)
        // O-update: per-thread d-slice t*4, all 8 heads
        float4 a0v = *(const float4*)&sAl[0];
        float4 a1v = *(const float4*)&sAl[4];
        float aa[8] = {a0v.x, a0v.y, a0v.z, a0v.w, a1v.x, a1v.y, a1v.z, a1v.w};
#pragma unroll
        for (int h = 0; h < 8; h++) {
            O[h][0] *= aa[h]; O[h][1] *= aa[h]; O[h][2] *= aa[h]; O[h][3] *= aa[h];
        }
#pragma unroll
        for (int r = 0; r < 4; r++) {
            float4 e0 = *(const float4*)&sEt[r][0];
            float4 e1 = *(const float4*)&sEt[r][4];
            float4 v = *(const float4*)&rows[r][t * 4];
            float ee[8] = {e0.x, e0.y, e0.z, e0.w, e1.x, e1.y, e1.z, e1.w};
#pragma unroll
            for (int h = 0; h < 8; h++) {
                O[h][0] += ee[h] * v.x; O[h][1] += ee[h] * v.y;
                O[h][2] += ee[h] * v.z; O[h][3] += ee[h] * v.w;
            }
        }
        cur ^= 1;
    }
#undef STAGE
    // write partials
    size_t pb = ((size_t)chunk * 64 + b) * 8;
#pragma unroll
    for (int h = 0; h < 8; h++)
        *(float4*)(Opart + (pb + h) * 1024 + t * 4) = make_float4(O[h][0], O[h][1], O[h][2], O[h][3]);
    if (lane == 0) {
        ml[(pb + h0) * 2 + 0] = m0h;
        ml[(pb + h0) * 2 + 1] = l0;
        ml[(pb + h0 + 1) * 2 + 0] = m1h;
        ml[(pb + h0 + 1) * 2 + 1] = l1;
    }
}

// ---------------- combine 16 chunk-partials -> common rows 1..8 (+bf16) ----------------
__global__ __launch_bounds__(256) void k_agg_reduce(const float* __restrict__ Opart,
                                                    const float* __restrict__ ml,
                                                    float* __restrict__ common,
                                                    unsigned short* __restrict__ common_bf) {
    int b = blockIdx.y, t = threadIdx.x;
    int d = blockIdx.x * 256 + t;
#pragma unroll
    for (int h = 0; h < 8; h++) {
        float mc[16], lc[16];
        float M = -1e30f;
#pragma unroll
        for (int c = 0; c < 16; c++) {
            size_t p = (((size_t)c * 64 + b) * 8 + h) * 2;
            mc[c] = ml[p]; lc[c] = ml[p + 1];
            M = fmaxf(M, mc[c]);
        }
        float den = 0.f, num = 0.f;
#pragma unroll
        for (int c = 0; c < 16; c++) {
            float sc = __expf(mc[c] - M);
            den += sc * lc[c];
            num += sc * Opart[(((size_t)c * 64 + b) * 8 + h) * 1024 + d];
        }
        float o = num / den;
        size_t off = ((size_t)(b * 9 + 1 + h) << 10) + d;
        common[off] = o;
        common_bf[off] = f2bf(o);
    }
}

// ---------------- 9x9 attention + diff -> bf16, grid (B) ----------------
__global__ __launch_bounds__(256) void k_diff(const float* __restrict__ Qd,
                                              const float* __restrict__ Kd,
                                              const float* __restrict__ common,
                                              const float* __restrict__ g,
                                              unsigned short* __restrict__ diffb_bf) {
    int b = blockIdx.x, t = threadIdx.x;
    int wave = t >> 6, lane = t & 63;
    __shared__ float sQ[9 * 1024];
    __shared__ float sK[9 * 1024];
    __shared__ float smd[81];
    __shared__ float sw[9];
    const float* Qb = Qd + (size_t)b * 9216;
    const float* Kb = Kd + (size_t)b * 9216;
    for (int i = t; i < 2304; i += 256) {
        *(float4*)&sQ[i * 4] = *(const float4*)(Qb + (size_t)i * 4);
        *(float4*)&sK[i * 4] = *(const float4*)(Kb + (size_t)i * 4);
    }
    __syncthreads();
    for (int p = wave; p < 81; p += 4) {
        int i = p / 9, j = p % 9;
        const float* qi = sQ + i * 1024;
        const float* kj = sK + j * 1024;
        float a = 0.f;
#pragma unroll
        for (int jj = 0; jj < 4; jj++) {
            float4 q = *(const float4*)(qi + jj * 256 + lane * 4);
            float4 k = *(const float4*)(kj + jj * 256 + lane * 4);
            a += q.x * k.x + q.y * k.y + q.z * k.z + q.w * k.w;
        }
        a = wred_sum(a);
        if (lane == 0) smd[p] = a * 0.03125f;
    }
    __syncthreads();
    if (t < 9) {
        float mx = -1e30f;
        for (int j = 0; j < 9; j++) mx = fmaxf(mx, smd[t * 9 + j]);
        float e[9], s = 0.f;
        for (int j = 0; j < 9; j++) { e[j] = __expf(smd[t * 9 + j] - mx); s += e[j]; }
        float inv = 1.f / s;
        for (int j = 0; j < 9; j++) smd[t * 9 + j] = e[j] * inv;
    }
    __syncthreads();
    if (t < 9) {
        float a = 0.f;
        for (int i = 0; i < 9; i++) a += smd[i * 9 + t];
        sw[t] = a * (1.f / 9.f);
    }
    __syncthreads();
    int d = t * 4;
    float4 ci = make_float4(0.f, 0.f, 0.f, 0.f);
#pragma unroll
    for (int j = 0; j < 9; j++) {
        float w = sw[j];
        float4 cv = *(const float4*)(common + ((size_t)(b * 9 + j) << 10) + d);
        ci.x += w * cv.x; ci.y += w * cv.y; ci.z += w * cv.z; ci.w += w * cv.w;
    }
    float4 gv = *(const float4*)(g + ((size_t)b << 10) + d);
    ushort4v u;
    u[0] = f2bf(gv.x - ci.x); u[1] = f2bf(gv.y - ci.y);
    u[2] = f2bf(gv.z - ci.z); u[3] = f2bf(gv.w - ci.w);
    *(ushort4v*)(diffb_bf + ((size_t)b << 10) + d) = u;
}

// ---------------- main GEMM: relu(Abf@W1t^T + dt2[b]) -> out. 128x128, BK=64, lds-dma ----------------
__global__ __launch_bounds__(256) void k_gemm_main(const unsigned short* __restrict__ A,
                                                   const unsigned short* __restrict__ Bw,
                                                   const float* __restrict__ dt2,
                                                   float* __restrict__ out) {
    __shared__ unsigned short As[128 * 64];
    __shared__ unsigned short Bs[128 * 64];
    int t = threadIdx.x;
    int lane = t & 63, wave = t >> 6;
    int quad = lane >> 4, l16 = lane & 15;
    int wr = wave >> 1, wc = wave & 1;
    int m0 = blockIdx.y * 128, n0 = blockIdx.x * 128;
    f32x4 acc[4][4];
#pragma unroll
    for (int i = 0; i < 4; i++)
#pragma unroll
        for (int j = 0; j < 4; j++)
#pragma unroll
            for (int rr = 0; rr < 4; rr++) acc[i][j][rr] = 0.f;

    for (int k0 = 0; k0 < DDIM; k0 += 64) {
#pragma unroll
        for (int cc = 0; cc < 4; cc++) {
            int o = cc * 4096 + t * 16;
            int r = o >> 7;
            int ke = (o & 127) >> 1;
            __builtin_amdgcn_global_load_lds(
                (gq_ptr)(const void*)(A + (size_t)(m0 + r) * DDIM + k0 + ke),
                (lds_ptr)(void*)((char*)As + o), 16, 0, 0);
            __builtin_amdgcn_global_load_lds(
                (gq_ptr)(const void*)(Bw + (size_t)(n0 + r) * DDIM + k0 + ke),
                (lds_ptr)(void*)((char*)Bs + o), 16, 0, 0);
        }
        __syncthreads();
#pragma unroll
        for (int ks = 0; ks < 2; ks++) {
            short8 af[4], bf[4];
#pragma unroll
            for (int tm = 0; tm < 4; tm++)
                af[tm] = *(const short8*)(As + (wr * 64 + tm * 16 + l16) * 64 + ks * 32 + quad * 8);
#pragma unroll
            for (int tn = 0; tn < 4; tn++)
                bf[tn] = *(const short8*)(Bs + (wc * 64 + tn * 16 + l16) * 64 + ks * 32 + quad * 8);
#pragma unroll
            for (int tm = 0; tm < 4; tm++)
#pragma unroll
                for (int tn = 0; tn < 4; tn++)
                    acc[tm][tn] = __builtin_amdgcn_mfma_f32_16x16x32_bf16(af[tm], bf[tn], acc[tm][tn], 0, 0, 0);
        }
        __syncthreads();
    }
#pragma unroll
    for (int tm = 0; tm < 4; tm++)
#pragma unroll
        for (int tn = 0; tn < 4; tn++) {
            int col = n0 + wc * 64 + tn * 16 + l16;
#pragma unroll
            for (int rr = 0; rr < 4; rr++) {
                int m = m0 + wr * 64 + tm * 16 + quad * 4 + rr;
                float v = acc[tm][tn][rr] + dt2[((size_t)(m & 63) << 10) + col];
                out[((size_t)m << 10) + col] = fmaxf(v, 0.f);
            }
        }
}

// ---------------- in-place LayerNorm over D ----------------
__global__ __launch_bounds__(256) void k_ln(float* __restrict__ io,
                                            const float* __restrict__ gamma,
                                            const float* __restrict__ beta) {
    size_t row = blockIdx.x;
    float* p = io + row * DDIM;
    int t = threadIdx.x;
    float4 v = *(const float4*)(p + t * 4);
    float s = v.x + v.y + v.z + v.w;
    float s2 = v.x * v.x + v.y * v.y + v.z * v.z + v.w * v.w;
    s = wred_sum(s);
    s2 = wred_sum(s2);
    __shared__ float r1[4], r2[4], mv[2];
    int wave = t >> 6, lane = t & 63;
    if (lane == 0) { r1[wave] = s; r2[wave] = s2; }
    __syncthreads();
    if (t == 0) {
        float S = r1[0] + r1[1] + r1[2] + r1[3];
        float S2 = r2[0] + r2[1] + r2[2] + r2[3];
        float mean = S * (1.f / DDIM);
        float var = S2 * (1.f / DDIM) - mean * mean;
        mv[0] = mean;
        mv[1] = rsqrtf(var + 1e-5f);
    }
    __syncthreads();
    float mean = mv[0], rstd = mv[1];
    float4 gg = *(const float4*)(gamma + t * 4);
    float4 bb = *(const float4*)(beta + t * 4);
    float4 o;
    o.x = (v.x - mean) * rstd * gg.x + bb.x;
    o.y = (v.y - mean) * rstd * gg.y + bb.y;
    o.z = (v.z - mean) * rstd * gg.z + bb.z;
    o.w = (v.w - mean) * rstd * gg.w + bb.w;
    *(float4*)(p + t * 4) = o;
}

extern "C" void kernel_launch(void* const* d_in, const int* in_sizes, int n_in,
                              void* d_out, int out_size, void* d_ws, size_t ws_size,
                              hipStream_t stream) {
    (void)in_sizes; (void)n_in; (void)out_size; (void)ws_size;
    const float* input = (const float*)d_in[0];
    const float* gn    = (const float*)d_in[1];
    const float* aWq   = (const float*)d_in[2];
    const float* abq   = (const float*)d_in[3];
    const float* aWk   = (const float*)d_in[4];
    const float* abk   = (const float*)d_in[5];
    const float* dWq   = (const float*)d_in[6];
    const float* dbq   = (const float*)d_in[7];
    const float* dWk   = (const float*)d_in[8];
    const float* dbk   = (const float*)d_in[9];
    const float* uW    = (const float*)d_in[10];
    const float* ub    = (const float*)d_in[11];
    const float* lng   = (const float*)d_in[12];
    const float* lnb   = (const float*)d_in[13];
    float* out = (float*)d_out;

    float* ws = (float*)d_ws;
    float* g      = ws;                       // 65536
    float* gpart  = g + 65536;                // 458752
    float* Q      = gpart + 458752;           // 524288  [h][b][d]
    float* Qt     = Q + 524288;               // 524288  [h][b][d]
    float* common = Qt + 524288;              // 589824  [b][9][d]
    float* dt2    = common + 589824;          // 65536
    float* Opart  = dt2 + 65536;              // 8388608 [c][b][h][d], 16 chunks
    float* ml     = Opart + 8388608;          // 16384
    float* qkb    = ml + 16384;               // 512
    float* Qd     = Opart;                    // alias: Opart dead after k_agg_reduce
    float* Kd     = Opart + 589824;
    unsigned short* Abf  = (unsigned short*)(qkb + 512);   // 12845056
    unsigned short* W1t  = Abf + 12845056;    // 1048576
    unsigned short* W2T  = W1t + 1048576;     // 1048576
    unsigned short* aWqT = W2T + 1048576;     // 8388608
    unsigned short* aWkb = aWqT + 8388608;    // 8388608
    unsigned short* dWqT = aWkb + 8388608;    // 1048576
    unsigned short* dWkT = dWqT + 1048576;    // 1048576
    unsigned short* g_bf = dWkT + 1048576;    // 65536
    unsigned short* Qbf  = g_bf + 65536;      // 524288
    unsigned short* cmbf = Qbf + 524288;      // 589824
    unsigned short* dfbf = cmbf + 589824;     // 65536

    k_prep_w<<<dim3(16, 16, 20), 256, 0, stream>>>(aWq, dWq, dWk, uW, aWk,
                                                   aWqT, dWqT, dWkT, W1t, W2T, aWkb);
    k_mean_cast<<<dim3(64, 7), 256, 0, stream>>>(input, Abf, gpart);
    k_gfinal<<<64, 256, 0, stream>>>(gpart, g, g_bf, common, cmbf);
    // Q[h,b,:] = g@aWqT[h] + abq[h]  (fp32 + bf16)
    k_mfma64<<<dim3(16, 1, 8), 256, 0, stream>>>(g_bf, aWqT, nullptr, abq, nullptr,
        Q, nullptr, Qbf, 0L, 1048576L, 1024L, 65536L, 8);
    // Qt[h,b,:] = Qbf[h]@aWkb[h]
    k_mfma64<<<dim3(16, 1, 8), 256, 0, stream>>>(Qbf, aWkb, nullptr, nullptr, nullptr,
        Qt, nullptr, nullptr, 65536L, 1048576L, 0L, 65536L, 8);
    k_qkb<<<64, 256, 0, stream>>>(Q, abk, qkb);
    k_agg<<<dim3(16, BDIM), 256, 0, stream>>>(gn, Qt, qkb, Opart, ml);
    k_agg_reduce<<<dim3(4, BDIM), 256, 0, stream>>>(Opart, ml, common, cmbf);
    // Qd = common@dWqT + dbq ; Kd = common@dWkT + dbk
    k_mfma64<<<dim3(16, 9, 2), 256, 0, stream>>>(cmbf, dWqT, dWkT, dbq, dbk,
        Qd, Kd, nullptr, 0L, 0L, 0L, 0L, 1);
    k_diff<<<BDIM, 256, 0, stream>>>(Qd, Kd, common, g, dfbf);
    // dt2 = diffb@W2 + ub
    k_mfma64<<<dim3(16, 1, 1), 256, 0, stream>>>(dfbf, W2T, nullptr, ub, nullptr,
        dt2, nullptr, nullptr, 0L, 0L, 0L, 0L, 1);
    k_gemm_main<<<dim3(8, 98), 256, 0, stream>>>(Abf, W1t, dt2, out);
    k_ln<<<SDIM * BDIM, 256, 0, stream>>>(out, lng, lnb);
}